// Round 1
// baseline (220.810 us; speedup 1.0000x reference)
//
#include <hip/hip_runtime.h>
#include <hip/hip_bf16.h>

// Gaussian upsampler: B=16, N=512, D=256, T derived from out_size.
// Outputs (flat): positions [B,T] (f32), out [B,T,D], weights [B,N,T].
//
// R8 structure: xpose (x f32 -> block-tiled bf16 X^T) -> scan (shfl cumsum)
//   -> pass1 (positions + iw2 + out1 via bf16 MFMA per 64-frame tile)
//   -> weights (contiguous streaming rows, zeros outside underflow band).
//
// R8 delta vs R7: pass1's B-operand was 64 scattered 4B f32 loads + 64 f2bf
// per thread (~380 VALU + 64 VMEM/thread — the dominant instruction cost).
// Now bf16 X^T is precomputed once in a tiled layout [b][d>>4][tok>>3][16][8]
// so each B-fragment is ONE aligned 16B load and a wave's loads coalesce into
// 4x256B segments. lo_u is rounded down to a multiple of 8 (window <=38 toks
// of the 64 K-pad; <=50 after alignment; clamped to 448 so tok <= 511).
// Extra tokens in [lo_u_aligned, l) underflow to w1==0 exactly (same MARGIN
// logic), so results are unchanged. Also: phase-A LDS writes regrouped to 2x
// ds_write_b128 (was 16x 8-way-conflicted u16), scan now shfl-based.
//
// Locality: ranges <= 4.0 and f32 expf underflows to 0 for |t-c| >= 10.3*r
// (arg <= -106 < ln(2^-149)). Durations >= 4 => a 64-frame tile + 2*42 margin
// spans <= 38 tokens; window cap 44, K-padded to 64 for MFMA.

#define TT  64       // frames per tile (pass 1)
#define NWC 44       // max valid window tokens
#define WBS 72       // wb bf16 row stride (144 B = 9*16: aligned b128 rows)
#define MARGIN 42.0f
#define RPB 4        // weight rows per block (pass 2)

typedef __attribute__((ext_vector_type(8))) short short8;
typedef __attribute__((ext_vector_type(8))) unsigned short ushort8;
typedef __attribute__((ext_vector_type(4))) float f32x4;

__device__ inline unsigned short f2bf(float f) {
    union { float f; unsigned int u; } v; v.f = f;
    unsigned int u = v.u;
    return (unsigned short)((u + 0x7FFFu + ((u >> 16) & 1u)) >> 16);  // RNE
}

// x [B,N,D] f32 -> xT bf16, tiled: xT[b][d>>4][tok>>3][d&15][tok&7]
// i.e. linear index b*131072 + ((d>>4)*64 + (tok>>3))*128 + (d&15)*8 + (tok&7)
__global__ __launch_bounds__(256) void xpose_kernel(
        const float* __restrict__ x, unsigned short* __restrict__ xT) {
    int n0 = blockIdx.x * 64, d0 = blockIdx.y * 64, b = blockIdx.z;
    int tid = threadIdx.x;
    __shared__ unsigned short tile[64][72];   // [n_local][d_local], padded
    const float* xb = x + ((size_t)b * 512 + n0) * 256 + d0;
    int dl = tid & 63, ng = tid >> 6;
    #pragma unroll
    for (int i = 0; i < 16; i++) {
        int nl = ng * 16 + i;
        tile[nl][dl] = f2bf(xb[(size_t)nl * 256 + dl]);   // 256B coalesced reads
    }
    __syncthreads();
    unsigned short* xTb = xT + (size_t)b * 131072;
    #pragma unroll
    for (int it = 0; it < 2; it++) {
        int ci  = it * 256 + tid;       // 0..511 chunk id (512 ushort8 per tile)
        int l15 = ci & 15;              // d within 16-subtile
        int sub = ci >> 4;              // 0..31: (dkb 0..3) x (tkb 0..7)
        int tkb = sub & 7, dkb = sub >> 3;
        ushort8 v;
        #pragma unroll
        for (int k = 0; k < 8; k++) v[k] = tile[tkb * 8 + k][dkb * 16 + l15];
        *(ushort8*)(xTb + ((((blockIdx.y * 4 + dkb) * 64) + blockIdx.x * 8 + tkb) << 7)
                        + (l15 << 3)) = v;  // consecutive tids -> consecutive 16B
    }
}

__global__ __launch_bounds__(512) void scan_kernel(
        const int* __restrict__ dur, const float* __restrict__ ranges,
        float* __restrict__ c, float* __restrict__ ir,
        int* __restrict__ e_i, int* __restrict__ st_i) {
    const int N = 512;
    int b = blockIdx.x, tid = threadIdx.x;
    int lane = tid & 63, wid = tid >> 6;
    int d = dur[b * N + tid];
    int v = d;
    #pragma unroll
    for (int off = 1; off < 64; off <<= 1) {
        int t = __shfl_up(v, off);
        if (lane >= off) v += t;
    }
    __shared__ int wsum[8], woff[8];
    if (lane == 63) wsum[wid] = v;
    __syncthreads();
    if (tid == 0) { int a = 0; for (int i = 0; i < 8; i++) { woff[i] = a; a += wsum[i]; } }
    __syncthreads();
    int e = v + woff[wid];
    float r = ranges[b * N + tid];
    c[b * N + tid]    = (float)e - 0.5f * (float)d;
    ir[b * N + tid]   = 1.0f / (r * r);
    e_i[b * N + tid]  = e;
    st_i[b * N + tid] = e - d;
}

// Pass 1: per (b, 64-frame tile): positions, iw2 -> ws, out1 via MFMA.
__global__ __launch_bounds__(256) void pass1_kernel(
        const unsigned short* __restrict__ xT, const float* __restrict__ c,
        const float* __restrict__ ir,
        const int* __restrict__ e_i, const int* __restrict__ st_i,
        float* __restrict__ pos_out /*[B,T]*/,
        float* __restrict__ out1 /*[B,T,D]*/,
        float* __restrict__ iw2_ws /*[B,T]*/,
        int T) {
    const int N = 512;
    const int D = 256;
    int b = blockIdx.y;
    int t0 = blockIdx.x * TT;
    int tid = threadIdx.x;

    __shared__ float c_s[512];
    __shared__ float ir_s[512];
    __shared__ int   es[512], ss[512];
    __shared__ __align__(16) unsigned short wb[TT][WBS]; // bf16 w1, K-padded
    __shared__ float part[4][TT];
    __shared__ float iw2_s[TT];
    __shared__ int lohi[2];

    for (int i = tid; i < 512; i += 256) {
        c_s[i]  = c[b * N + i];
        ir_s[i] = ir[b * N + i];
        es[i]   = e_i[b * N + i];
        ss[i]   = st_i[b * N + i];
    }
    __syncthreads();

    if (tid == 0) {
        float lo_v = (float)t0 - MARGIN;
        float hi_v = (float)(t0 + TT - 1) + MARGIN;
        int lo = 0, hi = 512;
        while (lo < hi) { int m = (lo + hi) >> 1; if (c_s[m] < lo_v) lo = m + 1; else hi = m; }
        int l = lo;
        lo = 0; hi = 512;
        while (lo < hi) { int m = (lo + hi) >> 1; if (c_s[m] <= hi_v) lo = m + 1; else hi = m; }
        int h = lo - 1;
        if (h > l + NWC - 1) h = l + NWC - 1;   // unreachable for dur>=4
        l &= ~7;                 // 8-align so X^T fragment loads are 16B-aligned
        if (l > 448) l = 448;    // keep tok range within [0,512)
        lohi[0] = l; lohi[1] = h;
    }
    // positions: one thread per tile frame
    if (tid < TT) {
        int t = t0 + tid;
        if (t < T) {
            int lo = 0, hi = 512;
            while (lo < hi) { int m = (lo + hi) >> 1; if (es[m] <= t) lo = m + 1; else hi = m; }
            int seg = min(lo, 511);
            pos_out[b * T + t] = (float)(t - ss[seg]);
        }
    }
    __syncthreads();
    int lo_u = lohi[0], hi_u = lohi[1];

    int tl = tid & 63;          // frame within tile
    int s  = tid >> 6;          // wave id
    int t  = t0 + tl;

    // Phase A: Gaussians for window (K-padded to 64), bf16 into wb, w2 partials.
    // Each thread owns 16 CONTIGUOUS columns [16s, 16s+16) of its row tl so the
    // LDS writes are 2x ds_write_b128 (was 16x 8-way-conflicted u16 stores).
    ushort8 wv0, wv1;
    float p = 0.f;
    #pragma unroll
    for (int jj = 0; jj < 16; jj++) {
        int n = lo_u + 16 * s + jj;
        float w1 = 0.f;
        if (n <= hi_u && t < T) {
            float dd = (float)t - c_s[n];
            w1 = expf(-ir_s[n] * dd * dd);   // underflows to 0 exactly like f32 ref
        }
        unsigned short hb = f2bf(w1);
        if (jj < 8) wv0[jj] = hb; else wv1[jj - 8] = hb;
        p += w1;
    }
    *(ushort8*)&wb[tl][16 * s]     = wv0;
    *(ushort8*)&wb[tl][16 * s + 8] = wv1;
    part[s][tl] = p;
    __syncthreads();
    if (tid < TT) {
        float w2 = part[0][tid] + part[1][tid] + part[2][tid] + part[3][tid];
        float iw2 = 1.0f / (w2 + 1e-20f);
        iw2_s[tid] = iw2;
        int t2 = t0 + tid;
        if (t2 < T) iw2_ws[b * T + t2] = iw2;   // re-read by weights_kernel
    }
    __syncthreads();

    // Phase C: MFMA. C[64t x 256d] = W[64 x 64] @ X[64 x 256].
    // Wave s owns d-slice [64s, 64s+64). B-fragment = ONE 16B load from the
    // tiled bf16 X^T (8 toks x fixed d, contiguous, aligned); per instruction
    // the wave's 64 lanes form 4x256B segments (fully coalesced, L2-resident).
    int lane = tid & 63;
    int l15  = lane & 15;
    int q    = lane >> 4;

    f32x4 acc[4][4];    // [mt][nt]
    #pragma unroll
    for (int mt = 0; mt < 4; mt++)
        #pragma unroll
        for (int nt = 0; nt < 4; nt++)
            acc[mt][nt] = (f32x4){0.f, 0.f, 0.f, 0.f};

    const unsigned short* xTb = xT + (size_t)b * 131072;
    #pragma unroll
    for (int ks = 0; ks < 2; ks++) {
        int tokb = (lo_u >> 3) + ks * 4 + q;      // token-block (8 toks)
        short8 afrag[4];
        #pragma unroll
        for (int mt = 0; mt < 4; mt++)
            afrag[mt] = *(const short8*)&wb[16 * mt + l15][ks * 32 + q * 8];
        #pragma unroll
        for (int nt = 0; nt < 4; nt++) {
            int dblk = 4 * s + nt;                // (64s + nt*16 + l15) >> 4
            short8 bfrag = *(const short8*)(xTb + (((dblk << 6) + tokb) << 7) + (l15 << 3));
            #pragma unroll
            for (int mt = 0; mt < 4; mt++)
                acc[mt][nt] = __builtin_amdgcn_mfma_f32_16x16x32_bf16(afrag[mt], bfrag, acc[mt][nt], 0, 0, 0);
        }
    }

    // Epilogue: C row = 16*mt + q*4 + r, cols 64s + nt*16 + l15
    #pragma unroll
    for (int mt = 0; mt < 4; mt++) {
        #pragma unroll
        for (int r = 0; r < 4; r++) {
            int tt = t0 + 16 * mt + q * 4 + r;
            if (tt < T) {
                float iw2 = iw2_s[16 * mt + q * 4 + r];
                float* orow = out1 + ((size_t)b * T + tt) * D + 64 * s;
                #pragma unroll
                for (int nt = 0; nt < 4; nt++)
                    orow[nt * 16 + l15] = acc[mt][nt][r] * iw2;
            }
        }
    }
}

// Pass 2: stream weights rows contiguously. Block = (b, RPB consecutive n).
__global__ __launch_bounds__(256) void weights_kernel(
        const float* __restrict__ c, const float* __restrict__ ir,
        const float* __restrict__ iw2_ws,
        float* __restrict__ out2 /*[B,N,T]*/, int T) {
    const int N = 512;
    int b = blockIdx.y;
    int n0 = blockIdx.x * RPB;
    int tid = threadIdx.x;
    const f32x4 z4 = (f32x4){0.f, 0.f, 0.f, 0.f};

    for (int r = 0; r < RPB; r++) {
        int n = n0 + r;
        float cn  = c[b * N + n];
        float irn = ir[b * N + n];
        float rad = 10.3f * __frsqrt_rn(irn) + 1.0f;  // outside => expf==0 in f32
        int lo = (int)(cn - rad); if (lo < 0) lo = 0;
        int hi = (int)(cn + rad) + 1; if (hi > T) hi = T;   // nonzero only in [lo, hi)

        size_t base = ((size_t)b * N + n) * (size_t)T;
        int head = (int)((4 - (base & 3)) & 3);             // floats to 16B alignment
        if (head > T) head = T;
        if (tid < head) {
            int t = tid;
            float w = 0.f;
            if (t >= lo && t < hi) {
                float d = (float)t - cn;
                w = expf(-irn * d * d) * iw2_ws[b * T + t];
            }
            out2[base + t] = w;
        }
        int ngrp = (T - head) >> 2;
        int tail = (T - head) & 3;
        float* rowp = (float*)(out2 + base + head);
        for (int g = tid; g < ngrp; g += 256) {
            int tg = head + 4 * g;
            f32x4 v = z4;
            if (tg + 3 >= lo && tg < hi) {
                #pragma unroll
                for (int k = 0; k < 4; k++) {
                    int t = tg + k;
                    if (t >= lo && t < hi) {
                        float d = (float)t - cn;
                        v[k] = expf(-irn * d * d) * iw2_ws[b * T + t];
                    }
                }
            }
            *(f32x4*)(rowp + 4 * g) = v;
        }
        if (tid < tail) {
            int t = head + 4 * ngrp + tid;
            float w = 0.f;
            if (t >= lo && t < hi) {
                float d = (float)t - cn;
                w = expf(-irn * d * d) * iw2_ws[b * T + t];
            }
            out2[base + t] = w;
        }
    }
}

extern "C" void kernel_launch(void* const* d_in, const int* in_sizes, int n_in,
                              void* d_out, int out_size, void* d_ws, size_t ws_size,
                              hipStream_t stream) {
    const float* x      = (const float*)d_in[0];
    const int*   dur    = (const int*)d_in[1];
    const float* ranges = (const float*)d_in[2];
    const int B = 16, N = 512, D = 256;
    const int T = out_size / (B * (1 + D + N));

    float* pos_out = (float*)d_out;
    float* out1    = pos_out + (size_t)B * T;
    float* out2    = out1 + (size_t)B * T * D;

    float* c      = (float*)d_ws;
    float* ir     = c + B * N;
    int*   e_i    = (int*)(ir + B * N);
    int*   st_i   = e_i + B * N;
    float* iw2_ws = (float*)(st_i + B * N);
    size_t xoff   = 4 * (size_t)(B * N) + (size_t)B * T;
    xoff = (xoff + 7) & ~(size_t)7;                       // 32B-align xT
    unsigned short* xT = (unsigned short*)((float*)d_ws + xoff);  // [B][16][64][16][8] bf16, 4 MB

    xpose_kernel<<<dim3(8, 4, B), 256, 0, stream>>>(x, xT);

    scan_kernel<<<B, 512, 0, stream>>>(dur, ranges, c, ir, e_i, st_i);

    dim3 g1((T + TT - 1) / TT, B);
    pass1_kernel<<<g1, 256, 0, stream>>>(xT, c, ir, e_i, st_i, pos_out, out1, iw2_ws, T);

    dim3 g2(N / RPB, B);
    weights_kernel<<<g2, 256, 0, stream>>>(c, ir, iw2_ws, out2, T);
}

// Round 2
// 211.619 us; speedup vs baseline: 1.0434x; 1.0434x over previous
//
#include <hip/hip_runtime.h>
#include <hip/hip_bf16.h>

// Gaussian upsampler: B=16, N=512, D=256, T derived from out_size.
// Outputs (flat): positions [B,T] (f32), out [B,T,D], weights [B,N,T].
//
// R9 structure: TWO launches (was four).
//   K1 (role-partitioned grid, 512 thr): scan (16 blk) || xpose f32->tiled
//     bf16 X^T (512 blk) || zero-fill of weights out2 (2048 blk, memset-rate
//     f32x4 grid-stride). The three roles are independent and now overlap.
//   K2 (pass1): positions + iw2 + out1 via bf16 MFMA per 64-frame tile,
//     PLUS the fused weights band: for window rows n in [lo_u,hi_u] each wave
//     writes out2[b][n][t0..t0+64) = expf(-ir*(t-c)^2)*iw2 (f32-exact, same
//     formula as the old weights_kernel; out-of-band values underflow to 0
//     over the K1 zeros). weights_kernel is DELETED: its launch, its c/ir/iw2
//     global re-reads, and its separate band pass.
//
// Coverage proof for the fusion: nonzero f32 weight requires |t-c| < 10.3*r
// <= 41.2 (expf underflows to exact 0 beyond). Window admits c in
// [t0-42, t0+63+42], so every (n,t) with nonzero weight and t in the tile has
// n inside the window. Tiles partition t => each (n,t) written exactly once.
// K1 zero-fill completes before K2 (kernel boundary) => no ordering race.
//
// R8 lesson (neutral delta): pass1 is store-bound, not instruction-bound;
// remaining levers are launch structure + pass fusion, hence R9.

#define TT  64       // frames per tile (pass 1)
#define NWC 44       // max valid window tokens
#define WBS 72       // wb bf16 row stride (144 B = 9*16: aligned b128 rows)
#define MARGIN 42.0f

#define SCB 16       // K1: scan blocks
#define XPB 512      // K1: xpose blocks
#define ZFB 2048     // K1: zero-fill blocks

typedef __attribute__((ext_vector_type(8))) short short8;
typedef __attribute__((ext_vector_type(8))) unsigned short ushort8;
typedef __attribute__((ext_vector_type(4))) float f32x4;

__device__ inline unsigned short f2bf(float f) {
    union { float f; unsigned int u; } v; v.f = f;
    unsigned int u = v.u;
    return (unsigned short)((u + 0x7FFFu + ((u >> 16) & 1u)) >> 16);  // RNE
}

// K1: blockIdx.x in [0,SCB): scan; [SCB,SCB+XPB): xpose; rest: zero-fill out2.
// xT layout: xT[b][d>>4][tok>>3][d&15][tok&7], linear
//   b*131072 + ((d>>4)*64 + (tok>>3))*128 + (d&15)*8 + (tok&7)
__global__ __launch_bounds__(512) void k1_combo(
        const float* __restrict__ x, const int* __restrict__ dur,
        const float* __restrict__ ranges,
        unsigned short* __restrict__ xT,
        float* __restrict__ c, float* __restrict__ ir,
        int* __restrict__ e_i, int* __restrict__ st_i,
        float* __restrict__ out2, int T) {
    const int N = 512;
    int bid = blockIdx.x, tid = threadIdx.x;

    __shared__ unsigned short tile[64][72];   // xpose staging (padded)
    __shared__ int wsum[8], woff[8];          // scan wave offsets

    if (bid < SCB) {
        // ---- scan: cumsum of durations, centers, 1/r^2 ----
        int b = bid;
        int lane = tid & 63, wid = tid >> 6;
        int d = dur[b * N + tid];
        int v = d;
        #pragma unroll
        for (int off = 1; off < 64; off <<= 1) {
            int t = __shfl_up(v, off);
            if (lane >= off) v += t;
        }
        if (lane == 63) wsum[wid] = v;
        __syncthreads();
        if (tid == 0) { int a = 0; for (int i = 0; i < 8; i++) { woff[i] = a; a += wsum[i]; } }
        __syncthreads();
        int e = v + woff[wid];
        float r = ranges[b * N + tid];
        c[b * N + tid]    = (float)e - 0.5f * (float)d;
        ir[b * N + tid]   = 1.0f / (r * r);
        e_i[b * N + tid]  = e;
        st_i[b * N + tid] = e - d;
    } else if (bid < SCB + XPB) {
        // ---- xpose: x f32 -> block-tiled bf16 X^T ----
        int v = bid - SCB;                    // (bx 0..7, by 0..3, b 0..15)
        int bx = v & 7, by = (v >> 3) & 3, b = v >> 5;
        int n0 = bx * 64, d0 = by * 64;
        const float* xb = x + ((size_t)b * 512 + n0) * 256 + d0;
        int dl = tid & 63, ng = tid >> 6;     // ng 0..7
        #pragma unroll
        for (int i = 0; i < 8; i++) {
            int nl = ng * 8 + i;
            tile[nl][dl] = f2bf(xb[(size_t)nl * 256 + dl]);   // 256B coalesced
        }
        __syncthreads();
        unsigned short* xTb = xT + (size_t)b * 131072;
        int ci  = tid;                        // 512 ushort8 chunks per tile
        int l15 = ci & 15;
        int sub = ci >> 4;                    // (dkb 0..3) x (tkb 0..7)
        int tkb = sub & 7, dkb = sub >> 3;
        ushort8 vv;
        #pragma unroll
        for (int k = 0; k < 8; k++) vv[k] = tile[tkb * 8 + k][dkb * 16 + l15];
        *(ushort8*)(xTb + ((((by * 4 + dkb) * 64) + bx * 8 + tkb) << 7)
                        + (l15 << 3)) = vv;   // consecutive tids -> consecutive 16B
    } else {
        // ---- zero-fill out2 [B,N,T] (memset-rate streaming) ----
        const f32x4 z4 = (f32x4){0.f, 0.f, 0.f, 0.f};
        f32x4* p = (f32x4*)out2;              // base 16B-aligned (64*257*T bytes off d_out)
        size_t nv4 = (size_t)2048 * (size_t)T;            // (16*512*T)/4, exact
        size_t stride = (size_t)ZFB * 512;
        for (size_t i = (size_t)(bid - SCB - XPB) * 512 + tid; i < nv4; i += stride)
            p[i] = z4;
    }
}

// K2: per (b, 64-frame tile): positions, iw2, out1 via MFMA, + weights band.
__global__ __launch_bounds__(256) void pass1_kernel(
        const unsigned short* __restrict__ xT, const float* __restrict__ c,
        const float* __restrict__ ir,
        const int* __restrict__ e_i, const int* __restrict__ st_i,
        float* __restrict__ pos_out /*[B,T]*/,
        float* __restrict__ out1 /*[B,T,D]*/,
        float* __restrict__ out2 /*[B,N,T]*/,
        int T) {
    const int N = 512;
    const int D = 256;
    int b = blockIdx.y;
    int t0 = blockIdx.x * TT;
    int tid = threadIdx.x;

    __shared__ float c_s[512];
    __shared__ float ir_s[512];
    __shared__ int   es[512], ss[512];
    __shared__ __align__(16) unsigned short wb[TT][WBS]; // bf16 w1, K-padded
    __shared__ float part[4][TT];
    __shared__ float iw2_s[TT];
    __shared__ int lohi[2];

    for (int i = tid; i < 512; i += 256) {
        c_s[i]  = c[b * N + i];
        ir_s[i] = ir[b * N + i];
        es[i]   = e_i[b * N + i];
        ss[i]   = st_i[b * N + i];
    }
    __syncthreads();

    if (tid == 0) {
        float lo_v = (float)t0 - MARGIN;
        float hi_v = (float)(t0 + TT - 1) + MARGIN;
        int lo = 0, hi = 512;
        while (lo < hi) { int m = (lo + hi) >> 1; if (c_s[m] < lo_v) lo = m + 1; else hi = m; }
        int l = lo;
        lo = 0; hi = 512;
        while (lo < hi) { int m = (lo + hi) >> 1; if (c_s[m] <= hi_v) lo = m + 1; else hi = m; }
        int h = lo - 1;
        if (h > l + NWC - 1) h = l + NWC - 1;   // unreachable for dur>=4
        l &= ~7;                 // 8-align so X^T fragment loads are 16B-aligned
        if (l > 448) l = 448;    // keep tok range within [0,512)
        lohi[0] = l; lohi[1] = h;
    }
    // positions: one thread per tile frame
    if (tid < TT) {
        int t = t0 + tid;
        if (t < T) {
            int lo = 0, hi = 512;
            while (lo < hi) { int m = (lo + hi) >> 1; if (es[m] <= t) lo = m + 1; else hi = m; }
            int seg = min(lo, 511);
            pos_out[b * T + t] = (float)(t - ss[seg]);
        }
    }
    __syncthreads();
    int lo_u = lohi[0], hi_u = lohi[1];

    int tl = tid & 63;          // frame within tile
    int s  = tid >> 6;          // wave id
    int t  = t0 + tl;

    // Phase A: Gaussians for window (K-padded to 64), bf16 into wb, w2 partials.
    // Thread owns 16 CONTIGUOUS columns [16s,16s+16) of row tl: 2x ds_write_b128.
    ushort8 wv0, wv1;
    float p = 0.f;
    #pragma unroll
    for (int jj = 0; jj < 16; jj++) {
        int n = lo_u + 16 * s + jj;
        float w1 = 0.f;
        if (n <= hi_u && t < T) {
            float dd = (float)t - c_s[n];
            w1 = expf(-ir_s[n] * dd * dd);   // underflows to 0 exactly like f32 ref
        }
        unsigned short hb = f2bf(w1);
        if (jj < 8) wv0[jj] = hb; else wv1[jj - 8] = hb;
        p += w1;
    }
    *(ushort8*)&wb[tl][16 * s]     = wv0;
    *(ushort8*)&wb[tl][16 * s + 8] = wv1;
    part[s][tl] = p;
    __syncthreads();
    if (tid < TT) {
        float w2 = part[0][tid] + part[1][tid] + part[2][tid] + part[3][tid];
        iw2_s[tid] = 1.0f / (w2 + 1e-20f);
    }
    __syncthreads();

    // Phase C: MFMA. C[64t x 256d] = W[64 x 64] @ X[64 x 256].
    // Wave s owns d-slice [64s, 64s+64). B-fragment = ONE aligned 16B load
    // from tiled bf16 X^T (wave forms 4x256B coalesced segments, L2-resident).
    int lane = tid & 63;
    int l15  = lane & 15;
    int q    = lane >> 4;

    f32x4 acc[4][4];    // [mt][nt]
    #pragma unroll
    for (int mt = 0; mt < 4; mt++)
        #pragma unroll
        for (int nt = 0; nt < 4; nt++)
            acc[mt][nt] = (f32x4){0.f, 0.f, 0.f, 0.f};

    const unsigned short* xTb = xT + (size_t)b * 131072;
    #pragma unroll
    for (int ks = 0; ks < 2; ks++) {
        int tokb = (lo_u >> 3) + ks * 4 + q;      // token-block (8 toks)
        short8 afrag[4];
        #pragma unroll
        for (int mt = 0; mt < 4; mt++)
            afrag[mt] = *(const short8*)&wb[16 * mt + l15][ks * 32 + q * 8];
        #pragma unroll
        for (int nt = 0; nt < 4; nt++) {
            int dblk = 4 * s + nt;                // (64s + nt*16 + l15) >> 4
            short8 bfrag = *(const short8*)(xTb + (((dblk << 6) + tokb) << 7) + (l15 << 3));
            #pragma unroll
            for (int mt = 0; mt < 4; mt++)
                acc[mt][nt] = __builtin_amdgcn_mfma_f32_16x16x32_bf16(afrag[mt], bfrag, acc[mt][nt], 0, 0, 0);
        }
    }

    // Epilogue: C row = 16*mt + q*4 + r, cols 64s + nt*16 + l15
    #pragma unroll
    for (int mt = 0; mt < 4; mt++) {
        #pragma unroll
        for (int r = 0; r < 4; r++) {
            int tt = t0 + 16 * mt + q * 4 + r;
            if (tt < T) {
                float iw2 = iw2_s[16 * mt + q * 4 + r];
                float* orow = out1 + ((size_t)b * T + tt) * D + 64 * s;
                #pragma unroll
                for (int nt = 0; nt < 4; nt++)
                    orow[nt * 16 + l15] = acc[mt][nt][r] * iw2;
            }
        }
    }

    // Fused weights band: wave s writes rows n = lo_u+s, +4, ... (<=13 rows),
    // 64 lanes cover t0..t0+63 => one contiguous 256B store per row.
    // f32-exact (fresh expf, NOT bf16 wb) — identical numerics to the old
    // weights_kernel; values outside the underflow band are exact 0 over the
    // K1 zero-fill.
    if (t < T) {
        float iw2l = iw2_s[tl];
        int nw = hi_u - lo_u + 1;
        for (int i = s; i < nw; i += 4) {
            int n = lo_u + i;
            float dd = (float)t - c_s[n];
            float w = expf(-ir_s[n] * dd * dd) * iw2l;
            out2[((size_t)b * N + n) * (size_t)T + t] = w;
        }
    }
}

extern "C" void kernel_launch(void* const* d_in, const int* in_sizes, int n_in,
                              void* d_out, int out_size, void* d_ws, size_t ws_size,
                              hipStream_t stream) {
    const float* x      = (const float*)d_in[0];
    const int*   dur    = (const int*)d_in[1];
    const float* ranges = (const float*)d_in[2];
    const int B = 16, N = 512, D = 256;
    const int T = out_size / (B * (1 + D + N));

    float* pos_out = (float*)d_out;
    float* out1    = pos_out + (size_t)B * T;
    float* out2    = out1 + (size_t)B * T * D;

    float* c      = (float*)d_ws;
    float* ir     = c + B * N;
    int*   e_i    = (int*)(ir + B * N);
    int*   st_i   = e_i + B * N;
    unsigned short* xT = (unsigned short*)(st_i + B * N);  // [B][16][64][16][8] bf16, 4 MB

    k1_combo<<<SCB + XPB + ZFB, 512, 0, stream>>>(x, dur, ranges, xT,
                                                  c, ir, e_i, st_i, out2, T);

    dim3 g1((T + TT - 1) / TT, B);
    pass1_kernel<<<g1, 256, 0, stream>>>(xT, c, ir, e_i, st_i,
                                         pos_out, out1, out2, T);
}

// Round 4
// 209.766 us; speedup vs baseline: 1.0526x; 1.0088x over previous
//
#include <hip/hip_runtime.h>
#include <hip/hip_bf16.h>

// Gaussian upsampler: B=16, N=512, D=256, T derived from out_size.
// Outputs (flat): positions [B,T] (f32), out [B,T,D], weights [B,N,T].
//
// R11 == R10 resubmitted verbatim (R10 bench died to container-acquire infra
// failure, not a kernel verdict; audit found no hang/fault candidates).
//
// R10 structure: TWO launches, fully-overlapped roles.
//   K0 (528 blk x 512 thr): scan (16 blk) || xpose f32 -> tiled bf16 X^T.
//   K1 (NP+2048 blk x 256 thr): pass1 role (positions + iw2 + out1 via bf16
//     MFMA + f32-exact weights band) || complement-fill role (zeros of out2
//     OUTSIDE each row's guaranteed band). The zero stream (126 MB) runs
//     concurrently with pass1 instead of serially before it (R9), and the
//     band is written exactly once (was zero-filled then overwritten).
//
// Disjointness proof: pass1 writes every (n,t) with t in
//   [ceil(c_n-42), floor(c_n+42)]  (such t forces c_n in [t0-42, t0+63+42]
//   of t's tile => n in that tile's window => band loop writes it).
// complement-fill writes only t outside that range, where |t-c| > 42 =>
//   expf arg <= -110 < ln(2^-149) => reference weight is EXACT 0.
// pass1's extra writes (window rows, t outside the range) are also exact 0,
// overlapping complement zeros value-identically (benign). Byte-disjoint
// same-line cross-block writes already exercised+passing in R9 (tile seams).
//
// History: R8 (bf16 X^T B-path) neutral => pass1 not instruction-bound.
// R9 (fuse weights band into pass1, delete weights_kernel) -9us.

#define TT  64       // frames per tile (pass 1)
#define NWC 44       // max valid window tokens
#define WBS 72       // wb bf16 row stride (144 B = 9*16: aligned b128 rows)
#define MARGIN 42.0f

#define SCB 16       // K0: scan blocks
#define XPB 512      // K0: xpose blocks
#define FB  2048     // K1: complement-fill blocks (4 rows each, 8192 rows)

typedef __attribute__((ext_vector_type(8))) short short8;
typedef __attribute__((ext_vector_type(8))) unsigned short ushort8;
typedef __attribute__((ext_vector_type(4))) float f32x4;

__device__ inline unsigned short f2bf(float f) {
    union { float f; unsigned int u; } v; v.f = f;
    unsigned int u = v.u;
    return (unsigned short)((u + 0x7FFFu + ((u >> 16) & 1u)) >> 16);  // RNE
}

// K0: blockIdx.x in [0,SCB): scan; [SCB,SCB+XPB): xpose.
// xT layout: xT[b][d>>4][tok>>3][d&15][tok&7], linear
//   b*131072 + ((d>>4)*64 + (tok>>3))*128 + (d&15)*8 + (tok&7)
__global__ __launch_bounds__(512) void k0_prep(
        const float* __restrict__ x, const int* __restrict__ dur,
        const float* __restrict__ ranges,
        unsigned short* __restrict__ xT,
        float* __restrict__ c, float* __restrict__ ir,
        int* __restrict__ e_i, int* __restrict__ st_i) {
    const int N = 512;
    int bid = blockIdx.x, tid = threadIdx.x;

    __shared__ unsigned short tile[64][72];   // xpose staging (padded)
    __shared__ int wsum[8], woff[8];          // scan wave offsets

    if (bid < SCB) {
        // ---- scan: cumsum of durations, centers, 1/r^2 ----
        int b = bid;
        int lane = tid & 63, wid = tid >> 6;
        int d = dur[b * N + tid];
        int v = d;
        #pragma unroll
        for (int off = 1; off < 64; off <<= 1) {
            int t = __shfl_up(v, off);
            if (lane >= off) v += t;
        }
        if (lane == 63) wsum[wid] = v;
        __syncthreads();
        if (tid == 0) { int a = 0; for (int i = 0; i < 8; i++) { woff[i] = a; a += wsum[i]; } }
        __syncthreads();
        int e = v + woff[wid];
        float r = ranges[b * N + tid];
        c[b * N + tid]    = (float)e - 0.5f * (float)d;
        ir[b * N + tid]   = 1.0f / (r * r);
        e_i[b * N + tid]  = e;
        st_i[b * N + tid] = e - d;
    } else {
        // ---- xpose: x f32 -> block-tiled bf16 X^T ----
        int v = bid - SCB;                    // (bx 0..7, by 0..3, b 0..15)
        int bx = v & 7, by = (v >> 3) & 3, b = v >> 5;
        int n0 = bx * 64, d0 = by * 64;
        const float* xb = x + ((size_t)b * 512 + n0) * 256 + d0;
        int dl = tid & 63, ng = tid >> 6;     // ng 0..7
        #pragma unroll
        for (int i = 0; i < 8; i++) {
            int nl = ng * 8 + i;
            tile[nl][dl] = f2bf(xb[(size_t)nl * 256 + dl]);   // 256B coalesced
        }
        __syncthreads();
        unsigned short* xTb = xT + (size_t)b * 131072;
        int ci  = tid;                        // 512 ushort8 chunks per tile
        int l15 = ci & 15;
        int sub = ci >> 4;                    // (dkb 0..3) x (tkb 0..7)
        int tkb = sub & 7, dkb = sub >> 3;
        ushort8 vv;
        #pragma unroll
        for (int k = 0; k < 8; k++) vv[k] = tile[tkb * 8 + k][dkb * 16 + l15];
        *(ushort8*)(xTb + ((((by * 4 + dkb) * 64) + bx * 8 + tkb) << 7)
                        + (l15 << 3)) = vv;   // consecutive tids -> consecutive 16B
    }
}

// K1: blocks [0, 16*ntiles): pass1 role; rest: complement zero-fill of out2.
__global__ __launch_bounds__(256) void k1_main(
        const unsigned short* __restrict__ xT, const float* __restrict__ c,
        const float* __restrict__ ir,
        const int* __restrict__ e_i, const int* __restrict__ st_i,
        float* __restrict__ pos_out /*[B,T]*/,
        float* __restrict__ out1 /*[B,T,D]*/,
        float* __restrict__ out2 /*[B,N,T]*/,
        int T, int ntiles) {
    const int N = 512;
    const int D = 256;
    int bid = blockIdx.x, tid = threadIdx.x;
    int NP = ntiles * 16;

    __shared__ float c_s[512];
    __shared__ float ir_s[512];
    __shared__ int   es[512], ss[512];
    __shared__ __align__(16) unsigned short wb[TT][WBS]; // bf16 w1, K-padded
    __shared__ float part[4][TT];
    __shared__ float iw2_s[TT];
    __shared__ int lohi[2];

    if (bid >= NP) {
        // ---- complement-fill: zeros of out2 outside each row's band ----
        int fid = bid - NP;
        const f32x4 z4 = (f32x4){0.f, 0.f, 0.f, 0.f};
        for (int r = 0; r < 4; r++) {
            int g = fid * 4 + r;              // row id 0..8191
            int b = g >> 9, n = g & 511;
            float cn = c[b * N + n];
            int zl = (int)ceilf(cn - 42.0f);  // complement: t < zl or t >= zh
            if (zl < 0) zl = 0; if (zl > T) zl = T;
            int zh = (int)(cn + 42.0f) + 1;   // floor(c+42)+1 (c+42 > 0)
            if (zh > T) zh = T; if (zh < zl) zh = zl;
            size_t base = ((size_t)b * N + n) * (size_t)T;
            int head = (int)((4 - (base & 3)) & 3);
            if (head > T) head = T;
            if (tid < head) {
                int t = tid;
                if (t < zl || t >= zh) out2[base + t] = 0.f;
            }
            int ngrp = (T - head) >> 2;
            int tail = (T - head) & 3;
            float* rowp = (float*)(out2 + base + head);
            for (int gg = tid; gg < ngrp; gg += 256) {
                int tg = head + 4 * gg;
                if (tg + 3 < zl || tg >= zh) {
                    *(f32x4*)(rowp + 4 * gg) = z4;          // 97.8% of groups
                } else if (tg < zl || tg + 3 >= zh) {
                    #pragma unroll
                    for (int k = 0; k < 4; k++) {
                        int t = tg + k;
                        if (t < zl || t >= zh) rowp[4 * gg + k] = 0.f;
                    }
                }
            }
            if (tid < tail) {
                int t = head + 4 * ngrp + tid;
                if (t < zl || t >= zh) out2[base + t] = 0.f;
            }
        }
        return;
    }

    // ---- pass1 role ----
    int b  = bid / ntiles;
    int t0 = (bid - b * ntiles) * TT;

    for (int i = tid; i < 512; i += 256) {
        c_s[i]  = c[b * N + i];
        ir_s[i] = ir[b * N + i];
        es[i]   = e_i[b * N + i];
        ss[i]   = st_i[b * N + i];
    }
    __syncthreads();

    if (tid == 0) {
        float lo_v = (float)t0 - MARGIN;
        float hi_v = (float)(t0 + TT - 1) + MARGIN;
        int lo = 0, hi = 512;
        while (lo < hi) { int m = (lo + hi) >> 1; if (c_s[m] < lo_v) lo = m + 1; else hi = m; }
        int l = lo;
        lo = 0; hi = 512;
        while (lo < hi) { int m = (lo + hi) >> 1; if (c_s[m] <= hi_v) lo = m + 1; else hi = m; }
        int h = lo - 1;
        if (h > l + NWC - 1) h = l + NWC - 1;   // unreachable for dur>=4
        l &= ~7;                 // 8-align so X^T fragment loads are 16B-aligned
        if (l > 448) l = 448;    // keep tok range within [0,512)
        lohi[0] = l; lohi[1] = h;
    }
    // positions: one thread per tile frame
    if (tid < TT) {
        int t = t0 + tid;
        if (t < T) {
            int lo = 0, hi = 512;
            while (lo < hi) { int m = (lo + hi) >> 1; if (es[m] <= t) lo = m + 1; else hi = m; }
            int seg = min(lo, 511);
            pos_out[b * T + t] = (float)(t - ss[seg]);
        }
    }
    __syncthreads();
    int lo_u = lohi[0], hi_u = lohi[1];

    int tl = tid & 63;          // frame within tile
    int s  = tid >> 6;          // wave id
    int t  = t0 + tl;

    // Phase A: Gaussians for window (K-padded to 64), bf16 into wb, w2 partials.
    // Thread owns 16 CONTIGUOUS columns [16s,16s+16) of row tl: 2x ds_write_b128.
    ushort8 wv0, wv1;
    float p = 0.f;
    #pragma unroll
    for (int jj = 0; jj < 16; jj++) {
        int n = lo_u + 16 * s + jj;
        float w1 = 0.f;
        if (n <= hi_u && t < T) {
            float dd = (float)t - c_s[n];
            w1 = expf(-ir_s[n] * dd * dd);   // underflows to 0 exactly like f32 ref
        }
        unsigned short hb = f2bf(w1);
        if (jj < 8) wv0[jj] = hb; else wv1[jj - 8] = hb;
        p += w1;
    }
    *(ushort8*)&wb[tl][16 * s]     = wv0;
    *(ushort8*)&wb[tl][16 * s + 8] = wv1;
    part[s][tl] = p;
    __syncthreads();
    if (tid < TT) {
        float w2 = part[0][tid] + part[1][tid] + part[2][tid] + part[3][tid];
        iw2_s[tid] = 1.0f / (w2 + 1e-20f);
    }
    __syncthreads();

    // Phase C: MFMA. C[64t x 256d] = W[64 x 64] @ X[64 x 256].
    // Wave s owns d-slice [64s, 64s+64). B-fragment = ONE aligned 16B load
    // from tiled bf16 X^T (wave forms 4x256B coalesced segments, L2-resident).
    int lane = tid & 63;
    int l15  = lane & 15;
    int q    = lane >> 4;

    f32x4 acc[4][4];    // [mt][nt]
    #pragma unroll
    for (int mt = 0; mt < 4; mt++)
        #pragma unroll
        for (int nt = 0; nt < 4; nt++)
            acc[mt][nt] = (f32x4){0.f, 0.f, 0.f, 0.f};

    const unsigned short* xTb = xT + (size_t)b * 131072;
    #pragma unroll
    for (int ks = 0; ks < 2; ks++) {
        int tokb = (lo_u >> 3) + ks * 4 + q;      // token-block (8 toks)
        short8 afrag[4];
        #pragma unroll
        for (int mt = 0; mt < 4; mt++)
            afrag[mt] = *(const short8*)&wb[16 * mt + l15][ks * 32 + q * 8];
        #pragma unroll
        for (int nt = 0; nt < 4; nt++) {
            int dblk = 4 * s + nt;                // (64s + nt*16 + l15) >> 4
            short8 bfrag = *(const short8*)(xTb + (((dblk << 6) + tokb) << 7) + (l15 << 3));
            #pragma unroll
            for (int mt = 0; mt < 4; mt++)
                acc[mt][nt] = __builtin_amdgcn_mfma_f32_16x16x32_bf16(afrag[mt], bfrag, acc[mt][nt], 0, 0, 0);
        }
    }

    // Epilogue: C row = 16*mt + q*4 + r, cols 64s + nt*16 + l15
    #pragma unroll
    for (int mt = 0; mt < 4; mt++) {
        #pragma unroll
        for (int r = 0; r < 4; r++) {
            int tt = t0 + 16 * mt + q * 4 + r;
            if (tt < T) {
                float iw2 = iw2_s[16 * mt + q * 4 + r];
                float* orow = out1 + ((size_t)b * T + tt) * D + 64 * s;
                #pragma unroll
                for (int nt = 0; nt < 4; nt++)
                    orow[nt * 16 + l15] = acc[mt][nt][r] * iw2;
            }
        }
    }

    // Fused weights band: wave s writes rows n = lo_u+s, +4, ... (<=13 rows),
    // 64 lanes cover t0..t0+63 => one contiguous 256B store per row.
    // f32-exact (fresh expf, NOT bf16 wb). Covers ALL t with |t-c_n| <= 42
    // (see header proof); complement-fill role writes the rest as zeros.
    if (t < T) {
        float iw2l = iw2_s[tl];
        int nw = hi_u - lo_u + 1;
        for (int i = s; i < nw; i += 4) {
            int n = lo_u + i;
            float dd = (float)t - c_s[n];
            float w = expf(-ir_s[n] * dd * dd) * iw2l;
            out2[((size_t)b * N + n) * (size_t)T + t] = w;
        }
    }
}

extern "C" void kernel_launch(void* const* d_in, const int* in_sizes, int n_in,
                              void* d_out, int out_size, void* d_ws, size_t ws_size,
                              hipStream_t stream) {
    const float* x      = (const float*)d_in[0];
    const int*   dur    = (const int*)d_in[1];
    const float* ranges = (const float*)d_in[2];
    const int B = 16, N = 512, D = 256;
    const int T = out_size / (B * (1 + D + N));

    float* pos_out = (float*)d_out;
    float* out1    = pos_out + (size_t)B * T;
    float* out2    = out1 + (size_t)B * T * D;

    float* c      = (float*)d_ws;
    float* ir     = c + B * N;
    int*   e_i    = (int*)(ir + B * N);
    int*   st_i   = e_i + B * N;
    unsigned short* xT = (unsigned short*)(st_i + B * N);  // [B][16][64][16][8] bf16, 4 MB

    k0_prep<<<SCB + XPB, 512, 0, stream>>>(x, dur, ranges, xT, c, ir, e_i, st_i);

    int ntiles = (T + TT - 1) / TT;
    k1_main<<<ntiles * 16 + FB, 256, 0, stream>>>(xT, c, ir, e_i, st_i,
                                                  pos_out, out1, out2, T, ntiles);
}

// Round 5
// 209.329 us; speedup vs baseline: 1.0548x; 1.0021x over previous
//
#include <hip/hip_runtime.h>
#include <hip/hip_bf16.h>

// Gaussian upsampler: B=16, N=512, D=256, T derived from out_size.
// Outputs (flat): positions [B,T] (f32), out [B,T,D], weights [B,N,T].
//
// R12 structure (same two launches as R10):
//   K0 (528 blk x 512 thr): scan (16 blk) || xpose f32 -> tiled bf16 X^T.
//   K1 (NP+2048 blk x 256 thr): pass1 role || complement-fill role.
//
// R12 delta vs R10: out1 epilogue now goes THROUGH LDS. R10 wrote out1 as
// 4x 64B segments at 4KB stride per wave-inst (MFMA C-fragment layout);
// 64 MB of out1 in 64B-granule multi-stream bursts is the one store path not
// matching the poison-fill's 1KB-contiguous fast pattern (fill measures
// 6.6 TB/s). Now each 16-row C chunk is staged into a reused LDS buffer
// (overlays dead es/ss/wb/part region -> no occupancy change) and each wave
// stores 4 FULL 1KB rows (64 lanes x f32x4). Values bit-identical.
//
// Disjointness proof (weights): pass1 writes every (n,t) with t in
//   [ceil(c_n-42), floor(c_n+42)] (such t forces c_n in [t0-42, t0+63+42]
//   of t's tile => n in that tile's window => band loop writes it).
// complement-fill writes only t outside that range, where |t-c| > 42 =>
//   expf arg <= -110 < ln(2^-149) => reference weight is EXACT 0. Overlap
//   writes are value-identical zeros (benign).
//
// History: R8 (bf16 X^T B-path) neutral => not instruction-bound.
// R9 (fuse weights band, delete weights_kernel) -9us. R10 (concurrent
// zero-fill) -1.9us => concurrency not the lever; bytes/store-pattern is.

#define TT  64       // frames per tile (pass 1)
#define NWC 44       // max valid window tokens
#define WBS 72       // wb bf16 row stride (144 B = 9*16: aligned b128 rows)
#define MARGIN 42.0f

#define SCB 16       // K0: scan blocks
#define XPB 512      // K0: xpose blocks
#define FB  2048     // K1: complement-fill blocks (4 rows each, 8192 rows)

typedef __attribute__((ext_vector_type(8))) short short8;
typedef __attribute__((ext_vector_type(8))) unsigned short ushort8;
typedef __attribute__((ext_vector_type(4))) float f32x4;

__device__ inline unsigned short f2bf(float f) {
    union { float f; unsigned int u; } v; v.f = f;
    unsigned int u = v.u;
    return (unsigned short)((u + 0x7FFFu + ((u >> 16) & 1u)) >> 16);  // RNE
}

// K0: blockIdx.x in [0,SCB): scan; [SCB,SCB+XPB): xpose.
// xT layout: xT[b][d>>4][tok>>3][d&15][tok&7], linear
//   b*131072 + ((d>>4)*64 + (tok>>3))*128 + (d&15)*8 + (tok&7)
__global__ __launch_bounds__(512) void k0_prep(
        const float* __restrict__ x, const int* __restrict__ dur,
        const float* __restrict__ ranges,
        unsigned short* __restrict__ xT,
        float* __restrict__ c, float* __restrict__ ir,
        int* __restrict__ e_i, int* __restrict__ st_i) {
    const int N = 512;
    int bid = blockIdx.x, tid = threadIdx.x;

    __shared__ unsigned short tile[64][72];   // xpose staging (padded)
    __shared__ int wsum[8], woff[8];          // scan wave offsets

    if (bid < SCB) {
        // ---- scan: cumsum of durations, centers, 1/r^2 ----
        int b = bid;
        int lane = tid & 63, wid = tid >> 6;
        int d = dur[b * N + tid];
        int v = d;
        #pragma unroll
        for (int off = 1; off < 64; off <<= 1) {
            int t = __shfl_up(v, off);
            if (lane >= off) v += t;
        }
        if (lane == 63) wsum[wid] = v;
        __syncthreads();
        if (tid == 0) { int a = 0; for (int i = 0; i < 8; i++) { woff[i] = a; a += wsum[i]; } }
        __syncthreads();
        int e = v + woff[wid];
        float r = ranges[b * N + tid];
        c[b * N + tid]    = (float)e - 0.5f * (float)d;
        ir[b * N + tid]   = 1.0f / (r * r);
        e_i[b * N + tid]  = e;
        st_i[b * N + tid] = e - d;
    } else {
        // ---- xpose: x f32 -> block-tiled bf16 X^T ----
        int v = bid - SCB;                    // (bx 0..7, by 0..3, b 0..15)
        int bx = v & 7, by = (v >> 3) & 3, b = v >> 5;
        int n0 = bx * 64, d0 = by * 64;
        const float* xb = x + ((size_t)b * 512 + n0) * 256 + d0;
        int dl = tid & 63, ng = tid >> 6;     // ng 0..7
        #pragma unroll
        for (int i = 0; i < 8; i++) {
            int nl = ng * 8 + i;
            tile[nl][dl] = f2bf(xb[(size_t)nl * 256 + dl]);   // 256B coalesced
        }
        __syncthreads();
        unsigned short* xTb = xT + (size_t)b * 131072;
        int ci  = tid;                        // 512 ushort8 chunks per tile
        int l15 = ci & 15;
        int sub = ci >> 4;                    // (dkb 0..3) x (tkb 0..7)
        int tkb = sub & 7, dkb = sub >> 3;
        ushort8 vv;
        #pragma unroll
        for (int k = 0; k < 8; k++) vv[k] = tile[tkb * 8 + k][dkb * 16 + l15];
        *(ushort8*)(xTb + ((((by * 4 + dkb) * 64) + bx * 8 + tkb) << 7)
                        + (l15 << 3)) = vv;   // consecutive tids -> consecutive 16B
    }
}

// K1: blocks [0, 16*ntiles): pass1 role; rest: complement zero-fill of out2.
__global__ __launch_bounds__(256) void k1_main(
        const unsigned short* __restrict__ xT, const float* __restrict__ c,
        const float* __restrict__ ir,
        const int* __restrict__ e_i, const int* __restrict__ st_i,
        float* __restrict__ pos_out /*[B,T]*/,
        float* __restrict__ out1 /*[B,T,D]*/,
        float* __restrict__ out2 /*[B,N,T]*/,
        int T, int ntiles) {
    const int N = 512;
    const int D = 256;
    int bid = blockIdx.x, tid = threadIdx.x;
    int NP = ntiles * 16;

    __shared__ float c_s[512];
    __shared__ float ir_s[512];
    __shared__ float iw2_s[TT];
    __shared__ int lohi[2];
    // Overlay region: phase use = es[512] + ss[512] + wb[TT][WBS] + part[4][TT]
    // (4096 + 9216 + 1024 = 14336 B); epilogue use = cbuf[16][260] f32
    // (16640 B). All phase arrays are dead before cbuf's first write.
    __shared__ __align__(16) char smem_u[16 * 260 * 4];
    int* es = (int*)smem_u;                               // [512]
    int* ss = es + 512;                                   // [512]
    unsigned short* wb = (unsigned short*)(ss + 512);     // [TT][WBS]
    float* part = (float*)(wb + TT * WBS);                // [4][TT]
    float (*cbuf)[260] = (float(*)[260])smem_u;           // [16][260]

    if (bid >= NP) {
        // ---- complement-fill: zeros of out2 outside each row's band ----
        int fid = bid - NP;
        const f32x4 z4 = (f32x4){0.f, 0.f, 0.f, 0.f};
        for (int r = 0; r < 4; r++) {
            int g = fid * 4 + r;              // row id 0..8191
            int b = g >> 9, n = g & 511;
            float cn = c[b * N + n];
            int zl = (int)ceilf(cn - 42.0f);  // complement: t < zl or t >= zh
            if (zl < 0) zl = 0; if (zl > T) zl = T;
            int zh = (int)(cn + 42.0f) + 1;   // floor(c+42)+1 (c+42 > 0)
            if (zh > T) zh = T; if (zh < zl) zh = zl;
            size_t base = ((size_t)b * N + n) * (size_t)T;
            int head = (int)((4 - (base & 3)) & 3);
            if (head > T) head = T;
            if (tid < head) {
                int t = tid;
                if (t < zl || t >= zh) out2[base + t] = 0.f;
            }
            int ngrp = (T - head) >> 2;
            int tail = (T - head) & 3;
            float* rowp = (float*)(out2 + base + head);
            for (int gg = tid; gg < ngrp; gg += 256) {
                int tg = head + 4 * gg;
                if (tg + 3 < zl || tg >= zh) {
                    *(f32x4*)(rowp + 4 * gg) = z4;          // 97.8% of groups
                } else if (tg < zl || tg + 3 >= zh) {
                    #pragma unroll
                    for (int k = 0; k < 4; k++) {
                        int t = tg + k;
                        if (t < zl || t >= zh) rowp[4 * gg + k] = 0.f;
                    }
                }
            }
            if (tid < tail) {
                int t = head + 4 * ngrp + tid;
                if (t < zl || t >= zh) out2[base + t] = 0.f;
            }
        }
        return;
    }

    // ---- pass1 role ----
    int b  = bid / ntiles;
    int t0 = (bid - b * ntiles) * TT;

    for (int i = tid; i < 512; i += 256) {
        c_s[i]  = c[b * N + i];
        ir_s[i] = ir[b * N + i];
        es[i]   = e_i[b * N + i];
        ss[i]   = st_i[b * N + i];
    }
    __syncthreads();

    if (tid == 0) {
        float lo_v = (float)t0 - MARGIN;
        float hi_v = (float)(t0 + TT - 1) + MARGIN;
        int lo = 0, hi = 512;
        while (lo < hi) { int m = (lo + hi) >> 1; if (c_s[m] < lo_v) lo = m + 1; else hi = m; }
        int l = lo;
        lo = 0; hi = 512;
        while (lo < hi) { int m = (lo + hi) >> 1; if (c_s[m] <= hi_v) lo = m + 1; else hi = m; }
        int h = lo - 1;
        if (h > l + NWC - 1) h = l + NWC - 1;   // unreachable for dur>=4
        l &= ~7;                 // 8-align so X^T fragment loads are 16B-aligned
        if (l > 448) l = 448;    // keep tok range within [0,512)
        lohi[0] = l; lohi[1] = h;
    }
    // positions: one thread per tile frame
    if (tid < TT) {
        int t = t0 + tid;
        if (t < T) {
            int lo = 0, hi = 512;
            while (lo < hi) { int m = (lo + hi) >> 1; if (es[m] <= t) lo = m + 1; else hi = m; }
            int seg = min(lo, 511);
            pos_out[b * T + t] = (float)(t - ss[seg]);
        }
    }
    __syncthreads();
    int lo_u = lohi[0], hi_u = lohi[1];

    int tl = tid & 63;          // frame within tile
    int s  = tid >> 6;          // wave id
    int t  = t0 + tl;

    // Phase A: Gaussians for window (K-padded to 64), bf16 into wb, w2 partials.
    // Thread owns 16 CONTIGUOUS columns [16s,16s+16) of row tl: 2x ds_write_b128.
    ushort8 wv0, wv1;
    float p = 0.f;
    #pragma unroll
    for (int jj = 0; jj < 16; jj++) {
        int n = lo_u + 16 * s + jj;
        float w1 = 0.f;
        if (n <= hi_u && t < T) {
            float dd = (float)t - c_s[n];
            w1 = expf(-ir_s[n] * dd * dd);   // underflows to 0 exactly like f32 ref
        }
        unsigned short hb = f2bf(w1);
        if (jj < 8) wv0[jj] = hb; else wv1[jj - 8] = hb;
        p += w1;
    }
    *(ushort8*)&wb[tl * WBS + 16 * s]     = wv0;
    *(ushort8*)&wb[tl * WBS + 16 * s + 8] = wv1;
    part[s * TT + tl] = p;
    __syncthreads();
    if (tid < TT) {
        float w2 = part[0 * TT + tid] + part[1 * TT + tid]
                 + part[2 * TT + tid] + part[3 * TT + tid];
        iw2_s[tid] = 1.0f / (w2 + 1e-20f);
    }
    __syncthreads();

    // Phase C: MFMA. C[64t x 256d] = W[64 x 64] @ X[64 x 256].
    // Wave s owns d-slice [64s, 64s+64). B-fragment = ONE aligned 16B load
    // from tiled bf16 X^T (wave forms 4x256B coalesced segments, L2-resident).
    int lane = tid & 63;
    int l15  = lane & 15;
    int q    = lane >> 4;

    f32x4 acc[4][4];    // [mt][nt]
    #pragma unroll
    for (int mt = 0; mt < 4; mt++)
        #pragma unroll
        for (int nt = 0; nt < 4; nt++)
            acc[mt][nt] = (f32x4){0.f, 0.f, 0.f, 0.f};

    const unsigned short* xTb = xT + (size_t)b * 131072;
    #pragma unroll
    for (int ks = 0; ks < 2; ks++) {
        int tokb = (lo_u >> 3) + ks * 4 + q;      // token-block (8 toks)
        short8 afrag[4];
        #pragma unroll
        for (int mt = 0; mt < 4; mt++)
            afrag[mt] = *(const short8*)&wb[(16 * mt + l15) * WBS + ks * 32 + q * 8];
        #pragma unroll
        for (int nt = 0; nt < 4; nt++) {
            int dblk = 4 * s + nt;                // (64s + nt*16 + l15) >> 4
            short8 bfrag = *(const short8*)(xTb + (((dblk << 6) + tokb) << 7) + (l15 << 3));
            #pragma unroll
            for (int mt = 0; mt < 4; mt++)
                acc[mt][nt] = __builtin_amdgcn_mfma_f32_16x16x32_bf16(afrag[mt], bfrag, acc[mt][nt], 0, 0, 0);
        }
    }

    // Epilogue via LDS: chunk g = rows [16g, 16g+16) (== mt g). Stage the
    // wave-scattered C fragments into cbuf, then each wave stores 4 FULL
    // 1KB rows (64 lanes x f32x4) — fill-pattern store efficiency.
    __syncthreads();                 // wb/part dead; cbuf overlays them
    #pragma unroll
    for (int g = 0; g < 4; g++) {
        #pragma unroll
        for (int r = 0; r < 4; r++) {
            float iw2 = iw2_s[16 * g + q * 4 + r];
            #pragma unroll
            for (int nt = 0; nt < 4; nt++)
                cbuf[q * 4 + r][64 * s + nt * 16 + l15] = acc[g][nt][r] * iw2;
        }
        __syncthreads();
        #pragma unroll
        for (int j = 0; j < 4; j++) {
            int row = 4 * s + j;
            int tt = t0 + 16 * g + row;
            if (tt < T) {
                f32x4 v = *(f32x4*)&cbuf[row][4 * lane];
                *(f32x4*)(out1 + ((size_t)b * T + tt) * D + 4 * lane) = v;
            }
        }
        __syncthreads();             // before next chunk overwrites cbuf
    }

    // Fused weights band: wave s writes rows n = lo_u+s, +4, ... (<=13 rows),
    // 64 lanes cover t0..t0+63 => one contiguous 256B store per row.
    // f32-exact (fresh expf, NOT bf16 wb). Covers ALL t with |t-c_n| <= 42
    // (see header proof); complement-fill role writes the rest as zeros.
    if (t < T) {
        float iw2l = iw2_s[tl];
        int nw = hi_u - lo_u + 1;
        for (int i = s; i < nw; i += 4) {
            int n = lo_u + i;
            float dd = (float)t - c_s[n];
            float w = expf(-ir_s[n] * dd * dd) * iw2l;
            out2[((size_t)b * N + n) * (size_t)T + t] = w;
        }
    }
}

extern "C" void kernel_launch(void* const* d_in, const int* in_sizes, int n_in,
                              void* d_out, int out_size, void* d_ws, size_t ws_size,
                              hipStream_t stream) {
    const float* x      = (const float*)d_in[0];
    const int*   dur    = (const int*)d_in[1];
    const float* ranges = (const float*)d_in[2];
    const int B = 16, N = 512, D = 256;
    const int T = out_size / (B * (1 + D + N));

    float* pos_out = (float*)d_out;
    float* out1    = pos_out + (size_t)B * T;
    float* out2    = out1 + (size_t)B * T * D;

    float* c      = (float*)d_ws;
    float* ir     = c + B * N;
    int*   e_i    = (int*)(ir + B * N);
    int*   st_i   = e_i + B * N;
    unsigned short* xT = (unsigned short*)(st_i + B * N);  // [B][16][64][16][8] bf16, 4 MB

    k0_prep<<<SCB + XPB, 512, 0, stream>>>(x, dur, ranges, xT, c, ir, e_i, st_i);

    int ntiles = (T + TT - 1) / TT;
    k1_main<<<ntiles * 16 + FB, 256, 0, stream>>>(xT, c, ir, e_i, st_i,
                                                  pos_out, out1, out2, T, ntiles);
}